// Round 3
// baseline (588.215 us; speedup 1.0000x reference)
//
#include <hip/hip_runtime.h>
#include <math.h>

// BiDirectionalSymplecticLayer via bf16 MFMA (16x16x32), fp32 state.
// Round 3: 2 blocks/CU. buf2 aliased onto bufS (legal: bufS is dead between
// L1's read and L4-epilogue's rewrite) -> LDS 84->67 KB; VGPRs pinned <=128
// via __launch_bounds__(512,4). Pack kernel rewritten coalesced (LDS-staged).
// Weights packed to MFMA B-fragment order in d_ws: mat 0=W1,1=W2,2=W2^T,3=W1^T.

#define TRB 32
#define AST 264              // bf16 row stride: 256 + 8 pad
#define SST 260              // fp32 S row stride (2-way-free bank spread)
#define DTV 0.1f

typedef __attribute__((ext_vector_type(8))) short short8;
typedef __attribute__((ext_vector_type(4))) float float4v;

__device__ __forceinline__ unsigned short f2bf(float f) {
  union { float f; unsigned u; } v; v.f = f;
  unsigned r = v.u + 0x7fff + ((v.u >> 16) & 1);   // RNE
  return (unsigned short)(r >> 16);
}

__device__ __forceinline__ float fast_tanh(float x) {
  float ax = fabsf(x);
  float e = __expf(2.0f * ax);
  float t = 1.0f - 2.0f * __builtin_amdgcn_rcpf(e + 1.0f);
  return x < 0.0f ? -t : t;
}

// Fragment order: ws[mat*65536 + ((kc*16+nt)*64+lane)*8 + j] = bf16(W[k][n]),
// k = kc*32 + (lane>>4)*8 + j, n = nt*16 + (lane&15); mats 2,3 use W[n][k].
// 32 blocks = 4 mats x 8 chunks; chunk = k-range (non-tr) or n-range (tr).
__global__ void __launch_bounds__(256)
pack_weights(const float* __restrict__ W1, const float* __restrict__ W2,
             unsigned short* __restrict__ ws) {
  __shared__ float tile[32 * 256];
  const int mat = blockIdx.x >> 3, ch = blockIdx.x & 7;
  const float* src = (mat == 0 || mat == 3) ? W1 : W2;
  const bool tr = (mat >= 2);
  for (int i = threadIdx.x; i < 32 * 256; i += 256)   // rows [ch*32, ch*32+32)
    tile[i] = src[ch * 32 * 256 + i];
  __syncthreads();
  const int lane = threadIdx.x & 63;
  const int quad = lane >> 4, l16 = lane & 15;
#pragma unroll
  for (int it = 0; it < 4; ++it) {
    int c = (threadIdx.x >> 6) * 4 + it;   // 0..15
    unsigned short v[8];
    int kc, nt;
    if (!tr) {               // chunk = kc = ch; c enumerates nt
      kc = ch; nt = c;
      int n = nt * 16 + l16;
#pragma unroll
      for (int j = 0; j < 8; ++j) v[j] = f2bf(tile[(quad * 8 + j) * 256 + n]);
    } else {                 // chunk covers n in [ch*32,+32): nt = 2ch + (c&1)
      kc = c >> 1; nt = 2 * ch + (c & 1);
      int nn = (c & 1) * 16 + l16;         // local row in tile
#pragma unroll
      for (int j = 0; j < 8; ++j) v[j] = f2bf(tile[nn * 256 + kc * 32 + quad * 8 + j]);
    }
    unsigned short* dst = ws + ((size_t)mat << 16) + (((kc * 16 + nt) * 64 + lane) << 3);
    *(short8*)dst = *(const short8*)v;
  }
}

// acc[m][t] += A(16m.., :) @ Wmat(:, wave*32+16t..), K=256.
__device__ __forceinline__ void mm_tiles(const unsigned short* Asrc,
                                         const unsigned short* __restrict__ wmat,
                                         int wave, int lane, float4v acc[2][2]) {
  const int quad = lane >> 4, l16 = lane & 15;
  acc[0][0] = acc[0][1] = acc[1][0] = acc[1][1] = (float4v){0.f, 0.f, 0.f, 0.f};
  const unsigned short* a0 = Asrc + l16 * AST + quad * 8;
  const unsigned short* a1 = a0 + 16 * AST;
  const int ntb = wave * 2;
#pragma unroll
  for (int kc = 0; kc < 8; ++kc) {
    short8 af0 = *(const short8*)(a0 + kc * 32);
    short8 af1 = *(const short8*)(a1 + kc * 32);
    short8 bf0 = *(const short8*)(wmat + (((kc * 16 + ntb) * 64 + lane) << 3));
    short8 bf1 = *(const short8*)(wmat + (((kc * 16 + ntb + 1) * 64 + lane) << 3));
    acc[0][0] = __builtin_amdgcn_mfma_f32_16x16x32_bf16(af0, bf0, acc[0][0], 0, 0, 0);
    acc[0][1] = __builtin_amdgcn_mfma_f32_16x16x32_bf16(af0, bf1, acc[0][1], 0, 0, 0);
    acc[1][0] = __builtin_amdgcn_mfma_f32_16x16x32_bf16(af1, bf0, acc[1][0], 0, 0, 0);
    acc[1][1] = __builtin_amdgcn_mfma_f32_16x16x32_bf16(af1, bf1, acc[1][1], 0, 0, 0);
  }
}

__global__ void __launch_bounds__(512, 4)
symplectic_mfma(const float* __restrict__ x,
                const float* __restrict__ b1, const float* __restrict__ b2,
                const float* __restrict__ Wout,
                const unsigned short* __restrict__ wpack,
                float* __restrict__ out) {
  __shared__ float S[TRB * SST];                       // fp32 state
  __shared__ __align__(16) unsigned short bufS[TRB * AST];  // bf16(S); also g2
  __shared__ __align__(16) unsigned short buf1[TRB * AST];  // h1 / g1

  const int tid = threadIdx.x;
  const int wave = tid >> 6, lane = tid & 63;
  const int quad = lane >> 4, l16 = lane & 15;
  const int b0 = blockIdx.x * TRB;
  const int col0 = wave * 32 + l16;        // tile t adds +16

  const float b1v[2] = {b1[col0], b1[col0 + 16]};
  const float b2v[2] = {b2[col0], b2[col0 + 16]};
  const float wov[2] = {Wout[col0], Wout[col0 + 16]};

  for (int dir = 0; dir < 2; ++dir) {
    const float dt = dir ? -DTV : DTV;
    const float hdt = 0.5f * dt;

    // init S = (q_mid | p_mid), bufS = bf16(S); emit mid cols once
    for (int idx = tid; idx < TRB * 256; idx += 512) {
      int r = idx >> 8, j = idx & 255;
      int b = b0 + r;
      const float* xb = x + ((size_t)(b * 64 + 32) << 7);
      float v = (j < 128) ? xb[j] : (xb[j - 128] - xb[j - 256]);
      S[r * SST + j] = v;
      bufS[r * AST + j] = f2bf(v);
      if (dir == 0) out[(size_t)b * 768 + 256 + j] = v;
    }
    __syncthreads();

    for (int hs = 0; hs < 8; ++hs) {
      const int half = hs & 1;
      float4v acc[2][2];
      float h1r[2][2][4];

      // L1: h1 = tanh(S @ W1 + b1) -> buf1 (+ regs)
      mm_tiles(bufS, wpack, wave, lane, acc);
#pragma unroll
      for (int m = 0; m < 2; ++m)
#pragma unroll
        for (int t = 0; t < 2; ++t)
#pragma unroll
          for (int r = 0; r < 4; ++r) {
            int row = m * 16 + quad * 4 + r;
            float h = fast_tanh(acc[m][t][r] + b1v[t]);
            h1r[m][t][r] = h;
            buf1[row * AST + col0 + t * 16] = f2bf(h);
          }
      __syncthreads();

      // L2: g2 = Wout * (1 - tanh(h1 @ W2 + b2)^2) -> bufS (aliased scratch;
      // old bf16 state is dead until L4's rewrite)
      mm_tiles(buf1, wpack + (1 << 16), wave, lane, acc);
#pragma unroll
      for (int m = 0; m < 2; ++m)
#pragma unroll
        for (int t = 0; t < 2; ++t)
#pragma unroll
          for (int r = 0; r < 4; ++r) {
            int row = m * 16 + quad * 4 + r;
            float h2 = fast_tanh(acc[m][t][r] + b2v[t]);
            bufS[row * AST + col0 + t * 16] = f2bf(wov[t] * (1.0f - h2 * h2));
          }
      __syncthreads();

      // L3: g1 = (g2 @ W2^T) * (1 - h1^2) -> buf1
      mm_tiles(bufS, wpack + (2 << 16), wave, lane, acc);
#pragma unroll
      for (int m = 0; m < 2; ++m)
#pragma unroll
        for (int t = 0; t < 2; ++t)
#pragma unroll
          for (int r = 0; r < 4; ++r) {
            int row = m * 16 + quad * 4 + r;
            float h = h1r[m][t][r];
            buf1[row * AST + col0 + t * 16] = f2bf(acc[m][t][r] * (1.0f - h * h));
          }
      __syncthreads();

      // L4: ds = g1 @ W1^T; leapfrog update of S; refresh bf16 mirror in bufS
      mm_tiles(buf1, wpack + (3 << 16), wave, lane, acc);
      if (wave < 4) {                       // ds cols < 128 -> p -= hdt*ds
#pragma unroll
        for (int m = 0; m < 2; ++m)
#pragma unroll
          for (int t = 0; t < 2; ++t) {
            int tc = col0 + t * 16 + 128;
#pragma unroll
            for (int r = 0; r < 4; ++r) {
              int row = m * 16 + quad * 4 + r;
              float nv = S[row * SST + tc] - hdt * acc[m][t][r];
              S[row * SST + tc] = nv;
              bufS[row * AST + tc] = f2bf(nv);
            }
          }
      } else {
        if (half == 0) {                    // ds cols >= 128 -> q += dt*ds
#pragma unroll
          for (int m = 0; m < 2; ++m)
#pragma unroll
            for (int t = 0; t < 2; ++t) {
              int tc = col0 + t * 16 - 128;
#pragma unroll
              for (int r = 0; r < 4; ++r) {
                int row = m * 16 + quad * 4 + r;
                float nv = S[row * SST + tc] + dt * acc[m][t][r];
                S[row * SST + tc] = nv;
                bufS[row * AST + tc] = f2bf(nv);
              }
            }
        } else {                            // q unchanged: restore bf16 mirror
#pragma unroll
          for (int m = 0; m < 2; ++m)
#pragma unroll
            for (int t = 0; t < 2; ++t) {
              int tc = col0 + t * 16 - 128;
#pragma unroll
              for (int r = 0; r < 4; ++r) {
                int row = m * 16 + quad * 4 + r;
                bufS[row * AST + tc] = f2bf(S[row * SST + tc]);
              }
            }
        }
      }
      __syncthreads();
    }

    const int obase = dir ? 0 : 512;        // fwd -> 512..767, bwd -> 0..255
    for (int idx = tid; idx < TRB * 256; idx += 512) {
      int r = idx >> 8, j = idx & 255;
      out[(size_t)(b0 + r) * 768 + obase + j] = S[r * SST + j];
    }
    __syncthreads();
  }
}

extern "C" void kernel_launch(void* const* d_in, const int* in_sizes, int n_in,
                              void* d_out, int out_size, void* d_ws, size_t ws_size,
                              hipStream_t stream) {
  const float* x    = (const float*)d_in[0];
  const float* W1   = (const float*)d_in[1];
  const float* b1   = (const float*)d_in[2];
  const float* W2   = (const float*)d_in[3];
  const float* b2   = (const float*)d_in[4];
  const float* Wout = (const float*)d_in[5];
  unsigned short* wpack = (unsigned short*)d_ws;   // 4 x 65536 bf16 = 512 KB
  float* out = (float*)d_out;

  hipLaunchKernelGGL(pack_weights, dim3(32), dim3(256), 0, stream, W1, W2, wpack);
  hipLaunchKernelGGL(symplectic_mfma, dim3(8192 / TRB), dim3(512), 0, stream,
                     x, b1, b2, Wout, wpack, out);
}

// Round 4
// 465.939 us; speedup vs baseline: 1.2624x; 1.2624x over previous
//
#include <hip/hip_runtime.h>
#include <math.h>

// BiDirectionalSymplecticLayer via bf16 MFMA (16x16x32), fp32 state.
// Round 4: undo the (512,4) VGPR clamp (it forced 64 VGPR -> ~950 MB scratch
// spill/dispatch, 1.7x regression). Keep 67 KB LDS (buf2 aliased onto bufS).
// Cut register demand instead: h1 re-read from buf1 in L3 epilogue (no h1r
// array, -16 VGPR) -> natural alloc <=128 -> 4 waves/EU -> 2 blocks/CU.
// Weights packed to MFMA B-fragment order in d_ws: mat 0=W1,1=W2,2=W2^T,3=W1^T.

#define TRB 32
#define AST 264              // bf16 row stride: 256 + 8 pad
#define SST 260              // fp32 S row stride
#define DTV 0.1f

typedef __attribute__((ext_vector_type(8))) short short8;
typedef __attribute__((ext_vector_type(4))) float float4v;

__device__ __forceinline__ unsigned short f2bf(float f) {
  union { float f; unsigned u; } v; v.f = f;
  unsigned r = v.u + 0x7fff + ((v.u >> 16) & 1);   // RNE
  return (unsigned short)(r >> 16);
}

__device__ __forceinline__ float bf2f(unsigned short b) {
  union { unsigned u; float f; } v; v.u = ((unsigned)b) << 16;
  return v.f;
}

__device__ __forceinline__ float fast_tanh(float x) {
  float ax = fabsf(x);
  float e = __expf(2.0f * ax);
  float t = 1.0f - 2.0f * __builtin_amdgcn_rcpf(e + 1.0f);
  return x < 0.0f ? -t : t;
}

// Fragment order: ws[mat*65536 + ((kc*16+nt)*64+lane)*8 + j] = bf16(W[k][n]),
// k = kc*32 + (lane>>4)*8 + j, n = nt*16 + (lane&15); mats 2,3 use W[n][k].
__global__ void __launch_bounds__(256)
pack_weights(const float* __restrict__ W1, const float* __restrict__ W2,
             unsigned short* __restrict__ ws) {
  __shared__ float tile[32 * 256];
  const int mat = blockIdx.x >> 3, ch = blockIdx.x & 7;
  const float* src = (mat == 0 || mat == 3) ? W1 : W2;
  const bool tr = (mat >= 2);
  for (int i = threadIdx.x; i < 32 * 256; i += 256)   // rows [ch*32, ch*32+32)
    tile[i] = src[ch * 32 * 256 + i];
  __syncthreads();
  const int lane = threadIdx.x & 63;
  const int quad = lane >> 4, l16 = lane & 15;
#pragma unroll
  for (int it = 0; it < 4; ++it) {
    int c = (threadIdx.x >> 6) * 4 + it;   // 0..15
    unsigned short v[8];
    int kc, nt;
    if (!tr) {               // chunk = kc = ch; c enumerates nt
      kc = ch; nt = c;
      int n = nt * 16 + l16;
#pragma unroll
      for (int j = 0; j < 8; ++j) v[j] = f2bf(tile[(quad * 8 + j) * 256 + n]);
    } else {                 // chunk covers n in [ch*32,+32): nt = 2ch + (c&1)
      kc = c >> 1; nt = 2 * ch + (c & 1);
      int nn = (c & 1) * 16 + l16;         // local row in tile
#pragma unroll
      for (int j = 0; j < 8; ++j) v[j] = f2bf(tile[nn * 256 + kc * 32 + quad * 8 + j]);
    }
    unsigned short* dst = ws + ((size_t)mat << 16) + (((kc * 16 + nt) * 64 + lane) << 3);
    *(short8*)dst = *(const short8*)v;
  }
}

// acc[m][t] += A(16m.., :) @ Wmat(:, wave*32+16t..), K=256.
__device__ __forceinline__ void mm_tiles(const unsigned short* Asrc,
                                         const unsigned short* __restrict__ wmat,
                                         int wave, int lane, float4v acc[2][2]) {
  const int quad = lane >> 4, l16 = lane & 15;
  acc[0][0] = acc[0][1] = acc[1][0] = acc[1][1] = (float4v){0.f, 0.f, 0.f, 0.f};
  const unsigned short* a0 = Asrc + l16 * AST + quad * 8;
  const unsigned short* a1 = a0 + 16 * AST;
  const int ntb = wave * 2;
#pragma unroll
  for (int kc = 0; kc < 8; ++kc) {
    short8 af0 = *(const short8*)(a0 + kc * 32);
    short8 af1 = *(const short8*)(a1 + kc * 32);
    short8 bf0 = *(const short8*)(wmat + (((kc * 16 + ntb) * 64 + lane) << 3));
    short8 bf1 = *(const short8*)(wmat + (((kc * 16 + ntb + 1) * 64 + lane) << 3));
    acc[0][0] = __builtin_amdgcn_mfma_f32_16x16x32_bf16(af0, bf0, acc[0][0], 0, 0, 0);
    acc[0][1] = __builtin_amdgcn_mfma_f32_16x16x32_bf16(af0, bf1, acc[0][1], 0, 0, 0);
    acc[1][0] = __builtin_amdgcn_mfma_f32_16x16x32_bf16(af1, bf0, acc[1][0], 0, 0, 0);
    acc[1][1] = __builtin_amdgcn_mfma_f32_16x16x32_bf16(af1, bf1, acc[1][1], 0, 0, 0);
  }
}

__global__ void __launch_bounds__(512)
symplectic_mfma(const float* __restrict__ x,
                const float* __restrict__ b1, const float* __restrict__ b2,
                const float* __restrict__ Wout,
                const unsigned short* __restrict__ wpack,
                float* __restrict__ out) {
  __shared__ float S[TRB * SST];                            // fp32 state
  __shared__ __align__(16) unsigned short bufS[TRB * AST];  // bf16(S); also g2
  __shared__ __align__(16) unsigned short buf1[TRB * AST];  // h1 / g1

  const int tid = threadIdx.x;
  const int wave = tid >> 6, lane = tid & 63;
  const int quad = lane >> 4, l16 = lane & 15;
  const int b0 = blockIdx.x * TRB;
  const int col0 = wave * 32 + l16;        // tile t adds +16

  const float b1v[2] = {b1[col0], b1[col0 + 16]};
  const float b2v[2] = {b2[col0], b2[col0 + 16]};
  const float wov[2] = {Wout[col0], Wout[col0 + 16]};

  for (int dir = 0; dir < 2; ++dir) {
    const float dt = dir ? -DTV : DTV;
    const float hdt = 0.5f * dt;

    // init S = (q_mid | p_mid), bufS = bf16(S); emit mid cols once
    for (int idx = tid; idx < TRB * 256; idx += 512) {
      int r = idx >> 8, j = idx & 255;
      int b = b0 + r;
      const float* xb = x + ((size_t)(b * 64 + 32) << 7);
      float v = (j < 128) ? xb[j] : (xb[j - 128] - xb[j - 256]);
      S[r * SST + j] = v;
      bufS[r * AST + j] = f2bf(v);
      if (dir == 0) out[(size_t)b * 768 + 256 + j] = v;
    }
    __syncthreads();

    for (int hs = 0; hs < 8; ++hs) {
      const int half = hs & 1;
      float4v acc[2][2];

      // L1: h1 = tanh(S @ W1 + b1) -> buf1
      mm_tiles(bufS, wpack, wave, lane, acc);
#pragma unroll
      for (int m = 0; m < 2; ++m)
#pragma unroll
        for (int t = 0; t < 2; ++t)
#pragma unroll
          for (int r = 0; r < 4; ++r) {
            int row = m * 16 + quad * 4 + r;
            buf1[row * AST + col0 + t * 16] = f2bf(fast_tanh(acc[m][t][r] + b1v[t]));
          }
      __syncthreads();

      // L2: g2 = Wout * (1 - tanh(h1 @ W2 + b2)^2) -> bufS (aliased scratch;
      // bf16 state is dead until the L4 epilogue rewrites it)
      mm_tiles(buf1, wpack + (1 << 16), wave, lane, acc);
#pragma unroll
      for (int m = 0; m < 2; ++m)
#pragma unroll
        for (int t = 0; t < 2; ++t)
#pragma unroll
          for (int r = 0; r < 4; ++r) {
            int row = m * 16 + quad * 4 + r;
            float h2 = fast_tanh(acc[m][t][r] + b2v[t]);
            bufS[row * AST + col0 + t * 16] = f2bf(wov[t] * (1.0f - h2 * h2));
          }
      __syncthreads();

      // L3: g1 = (g2 @ W2^T) * (1 - h1^2) -> buf1.  h1 re-read from buf1
      // (each thread reads exactly the element it then overwrites).
      mm_tiles(bufS, wpack + (2 << 16), wave, lane, acc);
#pragma unroll
      for (int m = 0; m < 2; ++m)
#pragma unroll
        for (int t = 0; t < 2; ++t)
#pragma unroll
          for (int r = 0; r < 4; ++r) {
            int row = m * 16 + quad * 4 + r;
            float h = bf2f(buf1[row * AST + col0 + t * 16]);
            buf1[row * AST + col0 + t * 16] = f2bf(acc[m][t][r] * (1.0f - h * h));
          }
      __syncthreads();

      // L4: ds = g1 @ W1^T; leapfrog update of S; refresh bf16 mirror in bufS
      mm_tiles(buf1, wpack + (3 << 16), wave, lane, acc);
      if (wave < 4) {                       // ds cols < 128 -> p -= hdt*ds
#pragma unroll
        for (int m = 0; m < 2; ++m)
#pragma unroll
          for (int t = 0; t < 2; ++t) {
            int tc = col0 + t * 16 + 128;
#pragma unroll
            for (int r = 0; r < 4; ++r) {
              int row = m * 16 + quad * 4 + r;
              float nv = S[row * SST + tc] - hdt * acc[m][t][r];
              S[row * SST + tc] = nv;
              bufS[row * AST + tc] = f2bf(nv);
            }
          }
      } else {
        if (half == 0) {                    // ds cols >= 128 -> q += dt*ds
#pragma unroll
          for (int m = 0; m < 2; ++m)
#pragma unroll
            for (int t = 0; t < 2; ++t) {
              int tc = col0 + t * 16 - 128;
#pragma unroll
              for (int r = 0; r < 4; ++r) {
                int row = m * 16 + quad * 4 + r;
                float nv = S[row * SST + tc] + dt * acc[m][t][r];
                S[row * SST + tc] = nv;
                bufS[row * AST + tc] = f2bf(nv);
              }
            }
        } else {                            // q unchanged: restore bf16 mirror
#pragma unroll
          for (int m = 0; m < 2; ++m)
#pragma unroll
            for (int t = 0; t < 2; ++t) {
              int tc = col0 + t * 16 - 128;
#pragma unroll
              for (int r = 0; r < 4; ++r) {
                int row = m * 16 + quad * 4 + r;
                bufS[row * AST + tc] = f2bf(S[row * SST + tc]);
              }
            }
        }
      }
      __syncthreads();
    }

    const int obase = dir ? 0 : 512;        // fwd -> 512..767, bwd -> 0..255
    for (int idx = tid; idx < TRB * 256; idx += 512) {
      int r = idx >> 8, j = idx & 255;
      out[(size_t)(b0 + r) * 768 + obase + j] = S[r * SST + j];
    }
    __syncthreads();
  }
}

extern "C" void kernel_launch(void* const* d_in, const int* in_sizes, int n_in,
                              void* d_out, int out_size, void* d_ws, size_t ws_size,
                              hipStream_t stream) {
  const float* x    = (const float*)d_in[0];
  const float* W1   = (const float*)d_in[1];
  const float* b1   = (const float*)d_in[2];
  const float* W2   = (const float*)d_in[3];
  const float* b2   = (const float*)d_in[4];
  const float* Wout = (const float*)d_in[5];
  unsigned short* wpack = (unsigned short*)d_ws;   // 4 x 65536 bf16 = 512 KB
  float* out = (float*)d_out;

  hipLaunchKernelGGL(pack_weights, dim3(32), dim3(256), 0, stream, W1, W2, wpack);
  hipLaunchKernelGGL(symplectic_mfma, dim3(8192 / TRB), dim3(512), 0, stream,
                     x, b1, b2, Wout, wpack, out);
}